// Round 5
// baseline (427.567 us; speedup 1.0000x reference)
//
#include <hip/hip_runtime.h>
#include <hip/hip_fp16.h>
#include <cstdint>
#include <cstddef>

#define N_NODES  100000
#define N_EDGES  3200000
#define N_GRAPHS 64

#define BQBITS   9
#define BQ       512                      // nodes per bucket
#define NBUCK    196                      // ceil(100000/512)
#define TILE     4096                     // edges per pass-1 block
#define NBLK     782                      // ceil(3200000/4096)

// ---------------- CSR build: bucketed 2-pass counting sort ----------------

__global__ void kp1_hist(const int* __restrict__ dst, int* __restrict__ gh, int ne) {
    __shared__ int h[NBUCK];
    for (int i = threadIdx.x; i < NBUCK; i += 256) h[i] = 0;
    __syncthreads();
    int base = blockIdx.x * TILE;
    for (int i = threadIdx.x; i < TILE; i += 256) {
        int e = base + i;
        if (e < ne) atomicAdd(&h[dst[e] >> BQBITS], 1);
    }
    __syncthreads();
    for (int i = threadIdx.x; i < NBUCK; i += 256) gh[i * NBLK + blockIdx.x] = h[i];
}

__global__ void kp1_scanA(int* __restrict__ gh, int* __restrict__ btotal) {
    int q = blockIdx.x;
    __shared__ int ts[256];
    int v[4];
    int tsum = 0;
#pragma unroll
    for (int u = 0; u < 4; ++u) {
        int idx = threadIdx.x * 4 + u;
        v[u] = (idx < NBLK) ? gh[q * NBLK + idx] : 0;
        tsum += v[u];
    }
    ts[threadIdx.x] = tsum;
    __syncthreads();
    for (int off = 1; off < 256; off <<= 1) {
        int t = (threadIdx.x >= off) ? ts[threadIdx.x - off] : 0;
        __syncthreads();
        ts[threadIdx.x] += t;
        __syncthreads();
    }
    int run = ts[threadIdx.x] - tsum;
#pragma unroll
    for (int u = 0; u < 4; ++u) {
        int idx = threadIdx.x * 4 + u;
        if (idx < NBLK) gh[q * NBLK + idx] = run;
        run += v[u];
    }
    if (threadIdx.x == 255) btotal[q] = ts[255];
}

__global__ void kp1_scanB(const int* __restrict__ btotal, int* __restrict__ bstart,
                          int* __restrict__ rs) {
    __shared__ int s[256];
    int v = (threadIdx.x < NBUCK) ? btotal[threadIdx.x] : 0;
    s[threadIdx.x] = v;
    __syncthreads();
    for (int off = 1; off < 256; off <<= 1) {
        int t = (threadIdx.x >= off) ? s[threadIdx.x - off] : 0;
        __syncthreads();
        s[threadIdx.x] += t;
        __syncthreads();
    }
    if (threadIdx.x < NBUCK) bstart[threadIdx.x] = s[threadIdx.x] - v;
    if (threadIdx.x == 0) { bstart[NBUCK] = N_EDGES; rs[N_NODES] = N_EDGES; }
}

__global__ void kp1_scatter(const int* __restrict__ src, const int* __restrict__ dst,
                            const int* __restrict__ gh, const int* __restrict__ bstart,
                            unsigned* __restrict__ tmp, int ne) {
    __shared__ int lcnt[NBUCK];
    __shared__ int lbase[NBUCK];
    for (int i = threadIdx.x; i < NBUCK; i += 256) {
        lcnt[i] = 0;
        lbase[i] = bstart[i] + gh[i * NBLK + blockIdx.x];
    }
    __syncthreads();
    int base = blockIdx.x * TILE;
    for (int i = threadIdx.x; i < TILE; i += 256) {
        int e = base + i;
        if (e >= ne) continue;
        int d = dst[e], s = src[e];
        int q = d >> BQBITS;
        int r = atomicAdd(&lcnt[q], 1);
        tmp[lbase[q] + r] = ((unsigned)(d & (BQ - 1)) << 17) | (unsigned)s;
    }
}

__global__ void kp2(const unsigned* __restrict__ tmp, const int* __restrict__ bstart,
                    int* __restrict__ rs, int* __restrict__ perm) {
    int q = blockIdx.x;
    int beg = bstart[q], end = bstart[q + 1];
    __shared__ int cnt[BQ];
    __shared__ int lofs[BQ];
    __shared__ int fill[BQ];
    if (threadIdx.x < BQ) { cnt[threadIdx.x] = 0; fill[threadIdx.x] = 0; }
    __syncthreads();
    for (int p = beg + threadIdx.x; p < end; p += 1024)
        atomicAdd(&cnt[tmp[p] >> 17], 1);
    __syncthreads();
    if (threadIdx.x < BQ) lofs[threadIdx.x] = cnt[threadIdx.x];
    __syncthreads();
    for (int off = 1; off < BQ; off <<= 1) {
        int t = 0;
        if (threadIdx.x < BQ && threadIdx.x >= off) t = lofs[threadIdx.x - off];
        __syncthreads();
        if (threadIdx.x < BQ) lofs[threadIdx.x] += t;   // inclusive
        __syncthreads();
    }
    if (threadIdx.x < BQ) {
        int node = q * BQ + threadIdx.x;
        if (node < N_NODES) rs[node] = beg + lofs[threadIdx.x] - cnt[threadIdx.x];
    }
    __syncthreads();
    for (int p = beg + threadIdx.x; p < end; p += 1024) {
        unsigned w = tmp[p];
        int dl = w >> 17;
        int s = w & 0x1FFFF;
        int r = atomicAdd(&fill[dl], 1);
        perm[beg + lofs[dl] - cnt[dl] + r] = s;
    }
}

// ---------------- transforms ----------------

// y1a/y1b (half, [N][8] each) = x @ W1l ; s1(f32,[N][16]) = x @ W1r + b1
__global__ void k_t1(const float* __restrict__ x, const float* __restrict__ W1l,
                     const float* __restrict__ W1r, const float* __restrict__ b1,
                     __half* __restrict__ y1a, __half* __restrict__ y1b,
                     float* __restrict__ s1, int n) {
    __shared__ float wl[64 * 16], wr[64 * 16], bb[16];
    for (int i = threadIdx.x; i < 64 * 16; i += blockDim.x) { wl[i] = W1l[i]; wr[i] = W1r[i]; }
    if (threadIdx.x < 16) bb[threadIdx.x] = b1[threadIdx.x];
    __syncthreads();
    int node = blockIdx.x * blockDim.x + threadIdx.x;
    if (node >= n) return;
    const float4* xr = reinterpret_cast<const float4*>(x + (size_t)node * 64);
    float accl[16], accr[16];
#pragma unroll
    for (int j = 0; j < 16; ++j) { accl[j] = 0.f; accr[j] = 0.f; }
#pragma unroll
    for (int q = 0; q < 16; ++q) {
        float4 v = xr[q];
        float xs[4] = {v.x, v.y, v.z, v.w};
#pragma unroll
        for (int u = 0; u < 4; ++u) {
            int k = q * 4 + u;
            float xv = xs[u];
#pragma unroll
            for (int j = 0; j < 16; ++j) {
                accl[j] += xv * wl[k * 16 + j];
                accr[j] += xv * wr[k * 16 + j];
            }
        }
    }
    alignas(16) __half yh[16];
#pragma unroll
    for (int j = 0; j < 16; ++j) yh[j] = __float2half(accl[j]);
    const uint4* yv = reinterpret_cast<const uint4*>(yh);
    reinterpret_cast<uint4*>(y1a + (size_t)node * 8)[0] = yv[0];
    reinterpret_cast<uint4*>(y1b + (size_t)node * 8)[0] = yv[1];
    float4* s4 = reinterpret_cast<float4*>(s1 + (size_t)node * 16);
#pragma unroll
    for (int q = 0; q < 4; ++q)
        s4[q] = make_float4(accr[q*4+0] + bb[q*4+0], accr[q*4+1] + bb[q*4+1],
                            accr[q*4+2] + bb[q*4+2], accr[q*4+3] + bb[q*4+3]);
}

// h2(f32) = [mean2a|mean2b] @ W2l + [ha|hb](half) @ W2r + b2      (16 -> 32)
__global__ void k_t2(const float* __restrict__ mean2a, const float* __restrict__ mean2b,
                     const __half* __restrict__ ha, const __half* __restrict__ hb,
                     const float* __restrict__ W2l, const float* __restrict__ W2r,
                     const float* __restrict__ b2, float* __restrict__ h2, int n) {
    __shared__ float wl[16 * 32], wr[16 * 32], bb[32];
    for (int i = threadIdx.x; i < 16 * 32; i += blockDim.x) { wl[i] = W2l[i]; wr[i] = W2r[i]; }
    if (threadIdx.x < 32) bb[threadIdx.x] = b2[threadIdx.x];
    __syncthreads();
    int node = blockIdx.x * blockDim.x + threadIdx.x;
    if (node >= n) return;
    float m[16], hh[16];
    {
        const float4* ma = reinterpret_cast<const float4*>(mean2a + (size_t)node * 8);
        const float4* mb = reinterpret_cast<const float4*>(mean2b + (size_t)node * 8);
        float4 a0 = ma[0], a1 = ma[1], b0 = mb[0], b1v = mb[1];
        m[0]=a0.x; m[1]=a0.y; m[2]=a0.z; m[3]=a0.w;
        m[4]=a1.x; m[5]=a1.y; m[6]=a1.z; m[7]=a1.w;
        m[8]=b0.x; m[9]=b0.y; m[10]=b0.z; m[11]=b0.w;
        m[12]=b1v.x; m[13]=b1v.y; m[14]=b1v.z; m[15]=b1v.w;
    }
    alignas(16) __half hv[16];
    reinterpret_cast<uint4*>(hv)[0] = reinterpret_cast<const uint4*>(ha + (size_t)node * 8)[0];
    reinterpret_cast<uint4*>(hv)[1] = reinterpret_cast<const uint4*>(hb + (size_t)node * 8)[0];
#pragma unroll
    for (int k = 0; k < 16; ++k) hh[k] = __half2float(hv[k]);
    float acc[32];
#pragma unroll
    for (int j = 0; j < 32; ++j) acc[j] = bb[j];
#pragma unroll
    for (int k = 0; k < 16; ++k) {
#pragma unroll
        for (int j = 0; j < 32; ++j)
            acc[j] += m[k] * wl[k * 32 + j] + hh[k] * wr[k * 32 + j];
    }
    float4* o4 = reinterpret_cast<float4*>(h2 + (size_t)node * 32);
#pragma unroll
    for (int q = 0; q < 8; ++q)
        o4[q] = make_float4(acc[q*4+0], acc[q*4+1], acc[q*4+2], acc[q*4+3]);
}

// z = relu(h2); y3a=[N][12] feats 0..11, y3b=[N][12] feats 12..20(+pad); s3=[N][21] f32
__global__ void k_t3(const float* __restrict__ h2, const float* __restrict__ W3l,
                     const float* __restrict__ W3r, const float* __restrict__ b3,
                     __half* __restrict__ y3a, __half* __restrict__ y3b,
                     float* __restrict__ s3, int n) {
    __shared__ float wl[32 * 21], wr[32 * 21], bb[21];
    for (int i = threadIdx.x; i < 32 * 21; i += blockDim.x) { wl[i] = W3l[i]; wr[i] = W3r[i]; }
    if (threadIdx.x < 21) bb[threadIdx.x] = b3[threadIdx.x];
    __syncthreads();
    int node = blockIdx.x * blockDim.x + threadIdx.x;
    if (node >= n) return;
    float z[32];
    const float4* h4 = reinterpret_cast<const float4*>(h2 + (size_t)node * 32);
#pragma unroll
    for (int q = 0; q < 8; ++q) {
        float4 v = h4[q];
        z[q*4+0] = fmaxf(v.x, 0.f); z[q*4+1] = fmaxf(v.y, 0.f);
        z[q*4+2] = fmaxf(v.z, 0.f); z[q*4+3] = fmaxf(v.w, 0.f);
    }
    float a[21], c[21];
#pragma unroll
    for (int j = 0; j < 21; ++j) { a[j] = 0.f; c[j] = bb[j]; }
#pragma unroll
    for (int k = 0; k < 32; ++k) {
#pragma unroll
        for (int j = 0; j < 21; ++j) {
            a[j] += z[k] * wl[k * 21 + j];
            c[j] += z[k] * wr[k * 21 + j];
        }
    }
    alignas(8) __half yha[12], yhb[12];
#pragma unroll
    for (int j = 0; j < 12; ++j) yha[j] = __float2half(a[j]);
#pragma unroll
    for (int j = 0; j < 9; ++j) yhb[j] = __float2half(a[12 + j]);
    yhb[9] = __half(0.f); yhb[10] = __half(0.f); yhb[11] = __half(0.f);
    uint2* pa = reinterpret_cast<uint2*>(y3a + (size_t)node * 12);
    uint2* pb = reinterpret_cast<uint2*>(y3b + (size_t)node * 12);
    const uint2* va = reinterpret_cast<const uint2*>(yha);
    const uint2* vb = reinterpret_cast<const uint2*>(yhb);
    pa[0] = va[0]; pa[1] = va[1]; pa[2] = va[2];
    pb[0] = vb[0]; pb[1] = vb[1]; pb[2] = vb[2];
    float* so = s3 + (size_t)node * 21;
#pragma unroll
    for (int j = 0; j < 21; ++j) so[j] = c[j];
}

// ------- aggregation: compact 8-feature half tables, 4 threads/node, half2 -------

template <bool RELU, bool SELF, bool OUT_HALF>
__global__ void k_aggH(const __half* __restrict__ y,     // [N][8] compact
                       const int* __restrict__ rs, const int* __restrict__ perm,
                       const float* __restrict__ self,   // [N][sstr], pre-offset column
                       int sstr,
                       void* __restrict__ outp,          // half[N][8] or float[N][8]
                       int n_nodes) {
    int t = blockIdx.x * blockDim.x + threadIdx.x;
    int node = t >> 2;
    int f = t & 3;                       // half2 lane: features 2f, 2f+1
    if (node >= n_nodes) return;
    const __half2* yp = reinterpret_cast<const __half2*>(y);
    int beg = rs[node], end = rs[node + 1];
    float ax = 0.f, ay = 0.f;
    int e = beg;
    for (; e + 4 <= end; e += 4) {
        int s0 = __builtin_nontemporal_load(&perm[e]);
        int s1 = __builtin_nontemporal_load(&perm[e + 1]);
        int s2 = __builtin_nontemporal_load(&perm[e + 2]);
        int s3 = __builtin_nontemporal_load(&perm[e + 3]);
        __half2 v0 = yp[(size_t)s0 * 4 + f];
        __half2 v1 = yp[(size_t)s1 * 4 + f];
        __half2 v2 = yp[(size_t)s2 * 4 + f];
        __half2 v3 = yp[(size_t)s3 * 4 + f];
        ax += (__low2float(v0) + __low2float(v1)) + (__low2float(v2) + __low2float(v3));
        ay += (__high2float(v0) + __high2float(v1)) + (__high2float(v2) + __high2float(v3));
    }
    for (; e < end; ++e) {
        int s = __builtin_nontemporal_load(&perm[e]);
        __half2 v = yp[(size_t)s * 4 + f];
        ax += __low2float(v);
        ay += __high2float(v);
    }
    float inv = 1.0f / fmaxf((float)(end - beg), 1.0f);
    ax *= inv; ay *= inv;
    if (SELF) {
        const float* sp = self + (size_t)node * sstr + f * 2;
        ax += __builtin_nontemporal_load(sp);
        ay += __builtin_nontemporal_load(sp + 1);
    }
    if (RELU) { ax = fmaxf(ax, 0.f); ay = fmaxf(ay, 0.f); }
    if constexpr (OUT_HALF) {
        __half2 hv = __floats2half2_rn(ax, ay);
        unsigned u = *reinterpret_cast<unsigned*>(&hv);
        __builtin_nontemporal_store(u, (unsigned*)outp + (size_t)node * 4 + f);
    } else {
        float* op = (float*)outp + (size_t)node * 8 + f * 2;
        __builtin_nontemporal_store(ax, op);
        __builtin_nontemporal_store(ay, op + 1);
    }
}

// layer-3 agg: [N][12] half table, 6 threads/node, writes f32 out stride 21 (+ s3)
__global__ void k_agg3(const __half* __restrict__ y,     // [N][12] compact
                       const int* __restrict__ rs, const int* __restrict__ perm,
                       const float* __restrict__ self,   // [N][21]
                       float* __restrict__ outp,         // [N][21]
                       int coff, int n_nodes) {
    int t = blockIdx.x * blockDim.x + threadIdx.x;
    int node = t / 6;
    int f = t - node * 6;                // features coff+2f, coff+2f+1
    if (node >= n_nodes) return;
    const __half2* yp = reinterpret_cast<const __half2*>(y);
    int beg = rs[node], end = rs[node + 1];
    float ax = 0.f, ay = 0.f;
    int e = beg;
    for (; e + 4 <= end; e += 4) {
        int s0 = __builtin_nontemporal_load(&perm[e]);
        int s1 = __builtin_nontemporal_load(&perm[e + 1]);
        int s2 = __builtin_nontemporal_load(&perm[e + 2]);
        int s3 = __builtin_nontemporal_load(&perm[e + 3]);
        __half2 v0 = yp[(size_t)s0 * 6 + f];
        __half2 v1 = yp[(size_t)s1 * 6 + f];
        __half2 v2 = yp[(size_t)s2 * 6 + f];
        __half2 v3 = yp[(size_t)s3 * 6 + f];
        ax += (__low2float(v0) + __low2float(v1)) + (__low2float(v2) + __low2float(v3));
        ay += (__high2float(v0) + __high2float(v1)) + (__high2float(v2) + __high2float(v3));
    }
    for (; e < end; ++e) {
        int s = __builtin_nontemporal_load(&perm[e]);
        __half2 v = yp[(size_t)s * 6 + f];
        ax += __low2float(v);
        ay += __high2float(v);
    }
    float inv = 1.0f / fmaxf((float)(end - beg), 1.0f);
    int c0 = coff + 2 * f, c1 = c0 + 1;
    if (c0 < 21) {
        float v = ax * inv + __builtin_nontemporal_load(&self[(size_t)node * 21 + c0]);
        __builtin_nontemporal_store(v, &outp[(size_t)node * 21 + c0]);
    }
    if (c1 < 21) {
        float v = ay * inv + __builtin_nontemporal_load(&self[(size_t)node * 21 + c1]);
        __builtin_nontemporal_store(v, &outp[(size_t)node * 21 + c1]);
    }
}

// ---------------- pooling + classifier ----------------

__device__ __forceinline__ int lowerb(const int* a, int n, int key) {
    int lo = 0, hi = n;
    while (lo < hi) { int mid = (lo + hi) >> 1; if (a[mid] < key) lo = mid + 1; else hi = mid; }
    return lo;
}

__global__ void k_pool(const float* __restrict__ h2, const int* __restrict__ batch,
                       float* __restrict__ gsum, float* __restrict__ gcnt, int n) {
    int g = blockIdx.x;
    __shared__ int sbeg, send;
    if (threadIdx.x == 0) { sbeg = lowerb(batch, n, g); send = lowerb(batch, n, g + 1); }
    __syncthreads();
    int beg = sbeg, end = send;
    int f = threadIdx.x & 31;
    int r = threadIdx.x >> 5;   // 8 row-groups
    float acc = 0.f;
    for (int i = beg + r; i < end; i += 8) acc += h2[(size_t)i * 32 + f];
    __shared__ float red[256];
    red[threadIdx.x] = acc;
    __syncthreads();
    if (r == 0) {
        float s = 0.f;
#pragma unroll
        for (int q = 0; q < 8; ++q) s += red[q * 32 + f];
        gsum[g * 32 + f] = s;
    }
    if (threadIdx.x == 0) gcnt[g] = (float)(end - beg);
}

__global__ void k_cls(const float* __restrict__ gsum, const float* __restrict__ gcnt,
                      const float* __restrict__ Wc, const float* __restrict__ bc,
                      float* __restrict__ outp) {
    int t = threadIdx.x;
    if (t >= N_GRAPHS * 10) return;
    int g = t / 10, c = t - g * 10;
    float cv = fmaxf(gcnt[g], 1.f);
    float acc = bc[c];
#pragma unroll
    for (int k = 0; k < 32; ++k) acc += (gsum[g * 32 + k] / cv) * Wc[k * 10 + c];
    outp[g * 10 + c] = acc;
}

// ---------------- launch ----------------

extern "C" void kernel_launch(void* const* d_in, const int* in_sizes, int n_in,
                              void* d_out, int out_size, void* d_ws, size_t ws_size,
                              hipStream_t stream) {
    const float* x    = (const float*)d_in[0];
    const int*   ei   = (const int*)d_in[1];
    const int*   batch= (const int*)d_in[2];
    const float* W1l  = (const float*)d_in[3];
    const float* b1   = (const float*)d_in[4];
    const float* W1r  = (const float*)d_in[5];
    const float* W2l  = (const float*)d_in[6];
    const float* b2   = (const float*)d_in[7];
    const float* W2r  = (const float*)d_in[8];
    const float* W3l  = (const float*)d_in[9];
    const float* b3   = (const float*)d_in[10];
    const float* W3r  = (const float*)d_in[11];
    const float* Wc   = (const float*)d_in[12];
    const float* bc   = (const float*)d_in[13];
    float* out = (float*)d_out;

    char* ws = (char*)d_ws;
    size_t off = 0;
    auto alloc = [&](size_t bytes) { size_t o = off; off += (bytes + 255) & ~(size_t)255; return o; };

    int*    rs    = (int*)(ws + alloc((size_t)(N_NODES + 1) * 4));
    int*    perm  = (int*)(ws + alloc((size_t)N_EDGES * 4));
    int*    gh    = (int*)(ws + alloc((size_t)NBUCK * NBLK * 4));
    int*    btotal= (int*)(ws + alloc(256 * 4));
    int*    bstart= (int*)(ws + alloc(260 * 4));
    __half* y1a   = (__half*)(ws + alloc((size_t)N_NODES * 8 * 2));
    __half* y1b   = (__half*)(ws + alloc((size_t)N_NODES * 8 * 2));
    float*  s1    = (float*)(ws + alloc((size_t)N_NODES * 16 * 4));
    __half* ha    = (__half*)(ws + alloc((size_t)N_NODES * 8 * 2));
    __half* hb    = (__half*)(ws + alloc((size_t)N_NODES * 8 * 2));
    float*  m2a   = (float*)(ws + alloc((size_t)N_NODES * 8 * 4));
    float*  m2b   = (float*)(ws + alloc((size_t)N_NODES * 8 * 4));
    float*  h2    = (float*)(ws + alloc((size_t)N_NODES * 32 * 4));
    __half* y3a   = (__half*)(ws + alloc((size_t)N_NODES * 12 * 2));
    __half* y3b   = (__half*)(ws + alloc((size_t)N_NODES * 12 * 2));
    float*  s3    = (float*)(ws + alloc((size_t)N_NODES * 21 * 4));
    float*  gsum  = (float*)(ws + alloc((size_t)N_GRAPHS * 32 * 4));
    float*  gcnt  = (float*)(ws + alloc((size_t)N_GRAPHS * 4));

    // tmp (12.8 MB) aliases h2 (12.8 MB): tmp dead before k_t2 writes h2
    unsigned* tmp = (unsigned*)h2;

    const int* src = ei;
    const int* dst = ei + N_EDGES;

    int nb = (N_NODES + 255) / 256;            // 391
    int gb4 = (N_NODES * 4 + 255) / 256;       // 4 threads/node passes
    int gb6 = (N_NODES * 6 + 255) / 256;       // 6 threads/node passes

    // CSR build (bucketed 2-pass counting sort, no global atomics)
    kp1_hist   <<<NBLK, 256, 0, stream>>>(dst, gh, N_EDGES);
    kp1_scanA  <<<NBUCK, 256, 0, stream>>>(gh, btotal);
    kp1_scanB  <<<1, 256, 0, stream>>>(btotal, bstart, rs);
    kp1_scatter<<<NBLK, 256, 0, stream>>>(src, dst, gh, bstart, tmp, N_EDGES);
    kp2        <<<NBUCK, 1024, 0, stream>>>(tmp, bstart, rs, perm);

    // layer 1: transform-first, split-feature aggregate (+self +relu) -> ha/hb (half)
    k_t1<<<nb, 256, 0, stream>>>(x, W1l, W1r, b1, y1a, y1b, s1, N_NODES);
    k_aggH<true, true, true><<<gb4, 256, 0, stream>>>(y1a, rs, perm, s1 + 0, 16, ha, N_NODES);
    k_aggH<true, true, true><<<gb4, 256, 0, stream>>>(y1b, rs, perm, s1 + 8, 16, hb, N_NODES);

    // layer 2: split-feature aggregate-first -> m2a/m2b (f32), then 16->32
    k_aggH<false, false, false><<<gb4, 256, 0, stream>>>(ha, rs, perm, nullptr, 0, m2a, N_NODES);
    k_aggH<false, false, false><<<gb4, 256, 0, stream>>>(hb, rs, perm, nullptr, 0, m2b, N_NODES);
    k_t2<<<nb, 256, 0, stream>>>(m2a, m2b, ha, hb, W2l, W2r, b2, h2, N_NODES);

    // layer 3: transform-first on relu(h2), split-feature aggregate, +self
    k_t3<<<nb, 256, 0, stream>>>(h2, W3l, W3r, b3, y3a, y3b, s3, N_NODES);
    k_agg3<<<gb6, 256, 0, stream>>>(y3a, rs, perm, s3, out + N_GRAPHS * 10, 0, N_NODES);
    k_agg3<<<gb6, 256, 0, stream>>>(y3b, rs, perm, s3, out + N_GRAPHS * 10, 12, N_NODES);

    // pooling over h2 (pre-relu) + classifier
    k_pool<<<N_GRAPHS, 256, 0, stream>>>(h2, batch, gsum, gcnt, N_NODES);
    k_cls<<<1, 640, 0, stream>>>(gsum, gcnt, Wc, bc, out);
}

// Round 6
// 293.006 us; speedup vs baseline: 1.4592x; 1.4592x over previous
//
#include <hip/hip_runtime.h>
#include <hip/hip_fp16.h>
#include <cstdint>
#include <cstddef>

#define N_NODES  100000
#define N_EDGES  3200000
#define N_GRAPHS 64

#define BQBITS   9
#define BQ       512                      // nodes per bucket
#define NBUCK    196                      // ceil(100000/512)
#define TILE     4096                     // edges per pass-1 block
#define NBLK     782                      // ceil(3200000/4096)
#define POOL_SLICES 8

// ---------------- CSR build: bucketed 2-pass counting sort ----------------

__global__ void kp1_hist(const int* __restrict__ dst, int* __restrict__ gh, int ne) {
    __shared__ int h[NBUCK];
    for (int i = threadIdx.x; i < NBUCK; i += 256) h[i] = 0;
    __syncthreads();
    int base = blockIdx.x * TILE;
    for (int i = threadIdx.x; i < TILE; i += 256) {
        int e = base + i;
        if (e < ne) atomicAdd(&h[dst[e] >> BQBITS], 1);
    }
    __syncthreads();
    for (int i = threadIdx.x; i < NBUCK; i += 256) gh[i * NBLK + blockIdx.x] = h[i];
}

__global__ void kp1_scanA(int* __restrict__ gh, int* __restrict__ btotal) {
    int q = blockIdx.x;
    __shared__ int ts[256];
    int v[4];
    int tsum = 0;
#pragma unroll
    for (int u = 0; u < 4; ++u) {
        int idx = threadIdx.x * 4 + u;
        v[u] = (idx < NBLK) ? gh[q * NBLK + idx] : 0;
        tsum += v[u];
    }
    ts[threadIdx.x] = tsum;
    __syncthreads();
    for (int off = 1; off < 256; off <<= 1) {
        int t = (threadIdx.x >= off) ? ts[threadIdx.x - off] : 0;
        __syncthreads();
        ts[threadIdx.x] += t;
        __syncthreads();
    }
    int run = ts[threadIdx.x] - tsum;
#pragma unroll
    for (int u = 0; u < 4; ++u) {
        int idx = threadIdx.x * 4 + u;
        if (idx < NBLK) gh[q * NBLK + idx] = run;
        run += v[u];
    }
    if (threadIdx.x == 255) btotal[q] = ts[255];
}

__global__ void kp1_scanB(const int* __restrict__ btotal, int* __restrict__ bstart,
                          int* __restrict__ rs) {
    __shared__ int s[256];
    int v = (threadIdx.x < NBUCK) ? btotal[threadIdx.x] : 0;
    s[threadIdx.x] = v;
    __syncthreads();
    for (int off = 1; off < 256; off <<= 1) {
        int t = (threadIdx.x >= off) ? s[threadIdx.x - off] : 0;
        __syncthreads();
        s[threadIdx.x] += t;
        __syncthreads();
    }
    if (threadIdx.x < NBUCK) bstart[threadIdx.x] = s[threadIdx.x] - v;
    if (threadIdx.x == 0) { bstart[NBUCK] = N_EDGES; rs[N_NODES] = N_EDGES; }
}

__global__ void kp1_scatter(const int* __restrict__ src, const int* __restrict__ dst,
                            const int* __restrict__ gh, const int* __restrict__ bstart,
                            unsigned* __restrict__ tmp, int ne) {
    __shared__ int lcnt[NBUCK];
    __shared__ int lbase[NBUCK];
    for (int i = threadIdx.x; i < NBUCK; i += 256) {
        lcnt[i] = 0;
        lbase[i] = bstart[i] + gh[i * NBLK + blockIdx.x];
    }
    __syncthreads();
    int base = blockIdx.x * TILE;
    for (int i = threadIdx.x; i < TILE; i += 256) {
        int e = base + i;
        if (e >= ne) continue;
        int d = dst[e], s = src[e];
        int q = d >> BQBITS;
        int r = atomicAdd(&lcnt[q], 1);
        tmp[lbase[q] + r] = ((unsigned)(d & (BQ - 1)) << 17) | (unsigned)s;
    }
}

__global__ void kp2(const unsigned* __restrict__ tmp, const int* __restrict__ bstart,
                    int* __restrict__ rs, int* __restrict__ perm) {
    int q = blockIdx.x;
    int beg = bstart[q], end = bstart[q + 1];
    __shared__ int cnt[BQ];
    __shared__ int lofs[BQ];
    __shared__ int fill[BQ];
    if (threadIdx.x < BQ) { cnt[threadIdx.x] = 0; fill[threadIdx.x] = 0; }
    __syncthreads();
    for (int p = beg + threadIdx.x; p < end; p += 1024)
        atomicAdd(&cnt[tmp[p] >> 17], 1);
    __syncthreads();
    if (threadIdx.x < BQ) lofs[threadIdx.x] = cnt[threadIdx.x];
    __syncthreads();
    for (int off = 1; off < BQ; off <<= 1) {
        int t = 0;
        if (threadIdx.x < BQ && threadIdx.x >= off) t = lofs[threadIdx.x - off];
        __syncthreads();
        if (threadIdx.x < BQ) lofs[threadIdx.x] += t;   // inclusive
        __syncthreads();
    }
    if (threadIdx.x < BQ) {
        int node = q * BQ + threadIdx.x;
        if (node < N_NODES) rs[node] = beg + lofs[threadIdx.x] - cnt[threadIdx.x];
    }
    __syncthreads();
    for (int p = beg + threadIdx.x; p < end; p += 1024) {
        unsigned w = tmp[p];
        int dl = w >> 17;
        int s = w & 0x1FFFF;
        int r = atomicAdd(&fill[dl], 1);
        perm[beg + lofs[dl] - cnt[dl] + r] = s;
    }
}

// ---------------- transforms ----------------

// y1(half) = x @ W1l ; s1(f32) = x @ W1r + b1      (64 -> 16)
__global__ void k_t1(const float* __restrict__ x, const float* __restrict__ W1l,
                     const float* __restrict__ W1r, const float* __restrict__ b1,
                     __half* __restrict__ y1, float* __restrict__ s1, int n) {
    __shared__ float wl[64 * 16], wr[64 * 16], bb[16];
    for (int i = threadIdx.x; i < 64 * 16; i += blockDim.x) { wl[i] = W1l[i]; wr[i] = W1r[i]; }
    if (threadIdx.x < 16) bb[threadIdx.x] = b1[threadIdx.x];
    __syncthreads();
    int node = blockIdx.x * blockDim.x + threadIdx.x;
    if (node >= n) return;
    const float4* xr = reinterpret_cast<const float4*>(x + (size_t)node * 64);
    float accl[16], accr[16];
#pragma unroll
    for (int j = 0; j < 16; ++j) { accl[j] = 0.f; accr[j] = 0.f; }
#pragma unroll
    for (int q = 0; q < 16; ++q) {
        float4 v = xr[q];
        float xs[4] = {v.x, v.y, v.z, v.w};
#pragma unroll
        for (int u = 0; u < 4; ++u) {
            int k = q * 4 + u;
            float xv = xs[u];
#pragma unroll
            for (int j = 0; j < 16; ++j) {
                accl[j] += xv * wl[k * 16 + j];
                accr[j] += xv * wr[k * 16 + j];
            }
        }
    }
    alignas(16) __half yh[16];
#pragma unroll
    for (int j = 0; j < 16; ++j) yh[j] = __float2half(accl[j]);
    uint4* y4 = reinterpret_cast<uint4*>(y1 + (size_t)node * 16);
    const uint4* yv = reinterpret_cast<const uint4*>(yh);
    y4[0] = yv[0]; y4[1] = yv[1];
    float4* s4 = reinterpret_cast<float4*>(s1 + (size_t)node * 16);
#pragma unroll
    for (int q = 0; q < 4; ++q)
        s4[q] = make_float4(accr[q*4+0] + bb[q*4+0], accr[q*4+1] + bb[q*4+1],
                            accr[q*4+2] + bb[q*4+2], accr[q*4+3] + bb[q*4+3]);
}

// h2(f32) = mean2 @ W2l + h(half) @ W2r + b2      (16 -> 32)
__global__ void k_t2(const float* __restrict__ mean2, const __half* __restrict__ h,
                     const float* __restrict__ W2l, const float* __restrict__ W2r,
                     const float* __restrict__ b2, float* __restrict__ h2, int n) {
    __shared__ float wl[16 * 32], wr[16 * 32], bb[32];
    for (int i = threadIdx.x; i < 16 * 32; i += blockDim.x) { wl[i] = W2l[i]; wr[i] = W2r[i]; }
    if (threadIdx.x < 32) bb[threadIdx.x] = b2[threadIdx.x];
    __syncthreads();
    int node = blockIdx.x * blockDim.x + threadIdx.x;
    if (node >= n) return;
    float m[16], hh[16];
    const float4* m4 = reinterpret_cast<const float4*>(mean2 + (size_t)node * 16);
#pragma unroll
    for (int q = 0; q < 4; ++q) {
        float4 a = m4[q];
        m[q*4+0]=a.x; m[q*4+1]=a.y; m[q*4+2]=a.z; m[q*4+3]=a.w;
    }
    alignas(16) __half hv[16];
    const uint4* hp = reinterpret_cast<const uint4*>(h + (size_t)node * 16);
    uint4* hvp = reinterpret_cast<uint4*>(hv);
    hvp[0] = hp[0]; hvp[1] = hp[1];
#pragma unroll
    for (int k = 0; k < 16; ++k) hh[k] = __half2float(hv[k]);
    float acc[32];
#pragma unroll
    for (int j = 0; j < 32; ++j) acc[j] = bb[j];
#pragma unroll
    for (int k = 0; k < 16; ++k) {
#pragma unroll
        for (int j = 0; j < 32; ++j)
            acc[j] += m[k] * wl[k * 32 + j] + hh[k] * wr[k * 32 + j];
    }
    float4* o4 = reinterpret_cast<float4*>(h2 + (size_t)node * 32);
#pragma unroll
    for (int q = 0; q < 8; ++q)
        o4[q] = make_float4(acc[q*4+0], acc[q*4+1], acc[q*4+2], acc[q*4+3]);
}

// z = relu(h2); y3(half, stride 24) = z @ W3l ; s3(f32) = z @ W3r + b3   (32 -> 21)
__global__ void k_t3(const float* __restrict__ h2, const float* __restrict__ W3l,
                     const float* __restrict__ W3r, const float* __restrict__ b3,
                     __half* __restrict__ y3, float* __restrict__ s3, int n) {
    __shared__ float wl[32 * 21], wr[32 * 21], bb[21];
    for (int i = threadIdx.x; i < 32 * 21; i += blockDim.x) { wl[i] = W3l[i]; wr[i] = W3r[i]; }
    if (threadIdx.x < 21) bb[threadIdx.x] = b3[threadIdx.x];
    __syncthreads();
    int node = blockIdx.x * blockDim.x + threadIdx.x;
    if (node >= n) return;
    float z[32];
    const float4* h4 = reinterpret_cast<const float4*>(h2 + (size_t)node * 32);
#pragma unroll
    for (int q = 0; q < 8; ++q) {
        float4 v = h4[q];
        z[q*4+0] = fmaxf(v.x, 0.f); z[q*4+1] = fmaxf(v.y, 0.f);
        z[q*4+2] = fmaxf(v.z, 0.f); z[q*4+3] = fmaxf(v.w, 0.f);
    }
    float a[21], c[21];
#pragma unroll
    for (int j = 0; j < 21; ++j) { a[j] = 0.f; c[j] = bb[j]; }
#pragma unroll
    for (int k = 0; k < 32; ++k) {
#pragma unroll
        for (int j = 0; j < 21; ++j) {
            a[j] += z[k] * wl[k * 21 + j];
            c[j] += z[k] * wr[k * 21 + j];
        }
    }
    alignas(16) __half yh[24];
#pragma unroll
    for (int j = 0; j < 21; ++j) yh[j] = __float2half(a[j]);
    yh[21] = __half(0.f); yh[22] = __half(0.f); yh[23] = __half(0.f);
    uint4* yp = reinterpret_cast<uint4*>(y3 + (size_t)node * 24);
    const uint4* yv = reinterpret_cast<const uint4*>(yh);
    yp[0] = yv[0]; yp[1] = yv[1]; yp[2] = yv[2];
    float* so = s3 + (size_t)node * 21;
#pragma unroll
    for (int j = 0; j < 21; ++j) so[j] = c[j];
}

// ---------------- aggregation (gather over CSR, fp16 table) ----------------

template <int F, int STRIDE, bool RELU, bool SELF, bool OUT_HALF>
__global__ void k_agg(const __half* __restrict__ y, const int* __restrict__ rs,
                      const int* __restrict__ perm, const float* __restrict__ self,
                      void* __restrict__ outp, int n_nodes) {
    int t = blockIdx.x * blockDim.x + threadIdx.x;
    int node = t / F;
    int f = t - node * F;
    if (node >= n_nodes) return;
    int beg = rs[node], end = rs[node + 1];
    float acc = 0.f;
    int e = beg;
    for (; e + 8 <= end; e += 8) {
        int s0 = __builtin_nontemporal_load(&perm[e]);
        int s1 = __builtin_nontemporal_load(&perm[e + 1]);
        int s2 = __builtin_nontemporal_load(&perm[e + 2]);
        int s3 = __builtin_nontemporal_load(&perm[e + 3]);
        int s4 = __builtin_nontemporal_load(&perm[e + 4]);
        int s5 = __builtin_nontemporal_load(&perm[e + 5]);
        int s6 = __builtin_nontemporal_load(&perm[e + 6]);
        int s7 = __builtin_nontemporal_load(&perm[e + 7]);
        float v0 = __half2float(y[(size_t)s0 * STRIDE + f]);
        float v1 = __half2float(y[(size_t)s1 * STRIDE + f]);
        float v2 = __half2float(y[(size_t)s2 * STRIDE + f]);
        float v3 = __half2float(y[(size_t)s3 * STRIDE + f]);
        float v4 = __half2float(y[(size_t)s4 * STRIDE + f]);
        float v5 = __half2float(y[(size_t)s5 * STRIDE + f]);
        float v6 = __half2float(y[(size_t)s6 * STRIDE + f]);
        float v7 = __half2float(y[(size_t)s7 * STRIDE + f]);
        acc += ((v0 + v1) + (v2 + v3)) + ((v4 + v5) + (v6 + v7));
    }
    for (; e < end; ++e) {
        int s = __builtin_nontemporal_load(&perm[e]);
        acc += __half2float(y[(size_t)s * STRIDE + f]);
    }
    float v = acc / fmaxf((float)(end - beg), 1.0f);
    if (SELF) v += __builtin_nontemporal_load(&self[(size_t)node * F + f]);
    if (RELU) v = fmaxf(v, 0.f);
    if constexpr (OUT_HALF) {
        __half hv = __float2half(v);
        unsigned short bits = *reinterpret_cast<unsigned short*>(&hv);
        __builtin_nontemporal_store(bits, (unsigned short*)outp + (size_t)node * F + f);
    } else {
        __builtin_nontemporal_store(v, (float*)outp + (size_t)node * F + f);
    }
}

// ---------------- pooling + classifier ----------------

__device__ __forceinline__ int lowerb(const int* a, int n, int key) {
    int lo = 0, hi = n;
    while (lo < hi) { int mid = (lo + hi) >> 1; if (a[mid] < key) lo = mid + 1; else hi = mid; }
    return lo;
}

// 8 slices per graph, 512 blocks; partial sums -> atomicAdd into zeroed gsum
__global__ void k_pool(const float* __restrict__ h2, const int* __restrict__ batch,
                       float* __restrict__ gsum, float* __restrict__ gcnt, int n) {
    int g = blockIdx.x / POOL_SLICES;
    int slice = blockIdx.x - g * POOL_SLICES;
    __shared__ int sbeg, send;
    if (threadIdx.x == 0) { sbeg = lowerb(batch, n, g); send = lowerb(batch, n, g + 1); }
    __syncthreads();
    int beg = sbeg, end = send;
    int f = threadIdx.x & 31;
    int r = threadIdx.x >> 5;   // 8 row-groups
    float acc = 0.f;
    for (int i = beg + slice * 8 + r; i < end; i += POOL_SLICES * 8)
        acc += h2[(size_t)i * 32 + f];
    __shared__ float red[256];
    red[threadIdx.x] = acc;
    __syncthreads();
    if (r == 0) {
        float s = 0.f;
#pragma unroll
        for (int q = 0; q < 8; ++q) s += red[q * 32 + f];
        atomicAdd(&gsum[g * 32 + f], s);
    }
    if (slice == 0 && threadIdx.x == 0) gcnt[g] = (float)(end - beg);
}

__global__ void k_cls(const float* __restrict__ gsum, const float* __restrict__ gcnt,
                      const float* __restrict__ Wc, const float* __restrict__ bc,
                      float* __restrict__ outp) {
    int t = threadIdx.x;
    if (t >= N_GRAPHS * 10) return;
    int g = t / 10, c = t - g * 10;
    float cv = fmaxf(gcnt[g], 1.f);
    float acc = bc[c];
#pragma unroll
    for (int k = 0; k < 32; ++k) acc += (gsum[g * 32 + k] / cv) * Wc[k * 10 + c];
    outp[g * 10 + c] = acc;
}

// ---------------- launch ----------------

extern "C" void kernel_launch(void* const* d_in, const int* in_sizes, int n_in,
                              void* d_out, int out_size, void* d_ws, size_t ws_size,
                              hipStream_t stream) {
    const float* x    = (const float*)d_in[0];
    const int*   ei   = (const int*)d_in[1];
    const int*   batch= (const int*)d_in[2];
    const float* W1l  = (const float*)d_in[3];
    const float* b1   = (const float*)d_in[4];
    const float* W1r  = (const float*)d_in[5];
    const float* W2l  = (const float*)d_in[6];
    const float* b2   = (const float*)d_in[7];
    const float* W2r  = (const float*)d_in[8];
    const float* W3l  = (const float*)d_in[9];
    const float* b3   = (const float*)d_in[10];
    const float* W3r  = (const float*)d_in[11];
    const float* Wc   = (const float*)d_in[12];
    const float* bc   = (const float*)d_in[13];
    float* out = (float*)d_out;

    char* ws = (char*)d_ws;
    size_t off = 0;
    auto alloc = [&](size_t bytes) { size_t o = off; off += (bytes + 255) & ~(size_t)255; return o; };

    int*    rs    = (int*)(ws + alloc((size_t)(N_NODES + 1) * 4));
    int*    perm  = (int*)(ws + alloc((size_t)N_EDGES * 4));
    int*    gh    = (int*)(ws + alloc((size_t)NBUCK * NBLK * 4));
    int*    btotal= (int*)(ws + alloc(256 * 4));
    int*    bstart= (int*)(ws + alloc(260 * 4));
    __half* y1    = (__half*)(ws + alloc((size_t)N_NODES * 16 * 2));
    float*  s1    = (float*)(ws + alloc((size_t)N_NODES * 16 * 4));
    __half* h     = (__half*)(ws + alloc((size_t)N_NODES * 16 * 2));
    float*  mean2 = (float*)(ws + alloc((size_t)N_NODES * 16 * 4));
    float*  h2    = (float*)(ws + alloc((size_t)N_NODES * 32 * 4));
    __half* y3    = (__half*)(ws + alloc((size_t)N_NODES * 24 * 2));
    float*  s3    = (float*)(ws + alloc((size_t)N_NODES * 21 * 4));
    float*  gsum  = (float*)(ws + alloc((size_t)N_GRAPHS * 32 * 4));
    float*  gcnt  = (float*)(ws + alloc((size_t)N_GRAPHS * 4));

    // tmp (12.8 MB) aliases h2 (12.8 MB): tmp dead before k_t2 writes h2
    unsigned* tmp = (unsigned*)h2;

    const int* src = ei;
    const int* dst = ei + N_EDGES;

    int nb = (N_NODES + 255) / 256;   // 391

    // CSR build (bucketed 2-pass counting sort, no global atomics)
    kp1_hist   <<<NBLK, 256, 0, stream>>>(dst, gh, N_EDGES);
    kp1_scanA  <<<NBUCK, 256, 0, stream>>>(gh, btotal);
    kp1_scanB  <<<1, 256, 0, stream>>>(btotal, bstart, rs);
    kp1_scatter<<<NBLK, 256, 0, stream>>>(src, dst, gh, bstart, tmp, N_EDGES);
    kp2        <<<NBUCK, 1024, 0, stream>>>(tmp, bstart, rs, perm);

    // layer 1: transform-first (64->16), aggregate 16 (fp16 table), +self, relu -> h (fp16)
    k_t1<<<nb, 256, 0, stream>>>(x, W1l, W1r, b1, y1, s1, N_NODES);
    k_agg<16, 16, true, true, true>
        <<<(N_NODES * 16 + 255) / 256, 256, 0, stream>>>(y1, rs, perm, s1, h, N_NODES);

    // layer 2: aggregate-first (16, fp16 table) -> mean2 (f32), then 16->32
    k_agg<16, 16, false, false, false>
        <<<(N_NODES * 16 + 255) / 256, 256, 0, stream>>>(h, rs, perm, nullptr, mean2, N_NODES);
    k_t2<<<nb, 256, 0, stream>>>(mean2, h, W2l, W2r, b2, h2, N_NODES);

    // layer 3: transform-first on relu(h2) (32->21, fp16 table stride 24), aggregate, +self
    k_t3<<<nb, 256, 0, stream>>>(h2, W3l, W3r, b3, y3, s3, N_NODES);
    k_agg<21, 24, false, true, false>
        <<<(N_NODES * 21 + 255) / 256, 256, 0, stream>>>(y3, rs, perm, s3, out + N_GRAPHS * 10, N_NODES);

    // pooling over h2 (pre-relu, zero gsum first) + classifier
    hipMemsetAsync(gsum, 0, (size_t)N_GRAPHS * 32 * 4, stream);
    k_pool<<<N_GRAPHS * POOL_SLICES, 256, 0, stream>>>(h2, batch, gsum, gcnt, N_NODES);
    k_cls<<<1, 640, 0, stream>>>(gsum, gcnt, Wc, bc, out);
}